// Round 4
// baseline (15340.417 us; speedup 1.0000x reference)
//
#include <hip/hip_runtime.h>
#include <hip/hip_bf16.h>
#include <math.h>

// Problem constants (match reference)
constexpr int kD = 1024;
constexpr int kH = 16;
constexpr int kDH = 64;     // head dim
constexpr int kV = 32000;
constexpr int kL = 8;
constexpr int kB = 2;
constexpr int kT = 1024;
constexpr int kRows = kB * kT;          // 2048 token rows
constexpr float kEPS = 1e-5f;

// ---------------------------------------------------------------------------
// Embedding: x[b,t,:] = emb[tokens[b,t],:] + pos_emb[t,:]
// ---------------------------------------------------------------------------
__global__ __launch_bounds__(256) void embed_kernel(
    const int* __restrict__ tokens, const float* __restrict__ emb,
    const float* __restrict__ pos, float* __restrict__ x)
{
    int row = blockIdx.x;               // b*T + t
    int t = row % kT;
    int tok = tokens[row];
    const float4* e = (const float4*)(emb + (size_t)tok * kD);
    const float4* p = (const float4*)(pos + (size_t)t * kD);
    float4* o = (float4*)(x + (size_t)row * kD);
    int i = threadIdx.x;                // 256 threads x float4 = 1024 floats
    float4 a = e[i], b4 = p[i];
    o[i] = make_float4(a.x + b4.x, a.y + b4.y, a.z + b4.z, a.w + b4.w);
}

// ---------------------------------------------------------------------------
// LayerNorm: one 256-thread block per row of D=1024
// ---------------------------------------------------------------------------
__global__ __launch_bounds__(256) void ln_kernel(
    const float* __restrict__ x, const float* __restrict__ sc,
    const float* __restrict__ bi, float* __restrict__ out)
{
    int row = blockIdx.x;
    int tid = threadIdx.x;
    float4 v4 = ((const float4*)(x + (size_t)row * kD))[tid];

    __shared__ float red1[4];
    __shared__ float red2[4];

    float s = v4.x + v4.y + v4.z + v4.w;
    #pragma unroll
    for (int off = 32; off > 0; off >>= 1) s += __shfl_down(s, off);
    if ((tid & 63) == 0) red1[tid >> 6] = s;
    __syncthreads();
    float mean = (red1[0] + red1[1] + red1[2] + red1[3]) * (1.0f / kD);

    float dx = v4.x - mean, dy = v4.y - mean, dz = v4.z - mean, dw = v4.w - mean;
    float vs = dx * dx + dy * dy + dz * dz + dw * dw;
    #pragma unroll
    for (int off = 32; off > 0; off >>= 1) vs += __shfl_down(vs, off);
    if ((tid & 63) == 0) red2[tid >> 6] = vs;
    __syncthreads();
    float var = (red2[0] + red2[1] + red2[2] + red2[3]) * (1.0f / kD);
    float inv = rsqrtf(var + kEPS);

    float4 s4 = ((const float4*)sc)[tid];
    float4 b4 = ((const float4*)bi)[tid];
    float4 o;
    o.x = dx * inv * s4.x + b4.x;
    o.y = dy * inv * s4.y + b4.y;
    o.z = dz * inv * s4.z + b4.z;
    o.w = dw * inv * s4.w + b4.w;
    ((float4*)(out + (size_t)row * kD))[tid] = o;
}

// ---------------------------------------------------------------------------
// SGEMM body: C[M,N] = A[M,K] @ W[K,N] + bias[N] (+ residual / gelu)
// 256 threads; per-thread TM x TN outputs; BK=16; register-prefetch pipeline.
// EPI: 0 = bias only, 1 = bias + residual add, 2 = bias + exact GELU
// Requires: M % BM == 0, N % BN == 0, K % 16 == 0.
// ---------------------------------------------------------------------------
template<int BM, int BN, int TM, int TN, int EPI>
__device__ __forceinline__ void gemm_body(
    const float* __restrict__ A, const float* __restrict__ W,
    const float* __restrict__ bias, const float* __restrict__ res,
    float* __restrict__ C, int M, int N, int K, int bm, int bn)
{
    constexpr int BK = 16;
    static_assert((BM / TM) * (BN / TN) == 256, "tile/micro-tile mismatch");
    constexpr int NX = BN / TN;                 // threads along n

    __shared__ __align__(16) float As[BK][BM + 4];
    __shared__ __align__(16) float Bs[BK][BN + 4];

    constexpr int A_SPR = BK / 4;               // float4 slots per A row
    constexpr int B_SPR = BN / 4;               // float4 slots per B k-row
    constexpr int A_PER = (BM * BK / 4) / 256;  // float4 loads per thread (A)
    constexpr int B_PER = (BK * BN / 4) / 256;  // float4 loads per thread (B)
    static_assert(A_PER >= 1 && B_PER >= 1, "tile too small");

    int tid = threadIdx.x;
    int tx = tid % NX;
    int ty = tid / NX;

    float acc[TM][TN] = {};
    float4 pa[A_PER], pb[B_PER];

    // ---- prologue: load tile 0 into regs, store to LDS ----
    #pragma unroll
    for (int i = 0; i < A_PER; ++i) {
        int slot = i * 256 + tid;
        int row = slot / A_SPR, c4 = (slot % A_SPR) * 4;
        pa[i] = *(const float4*)(A + (size_t)(bm + row) * K + c4);
    }
    #pragma unroll
    for (int i = 0; i < B_PER; ++i) {
        int slot = i * 256 + tid;
        int krow = slot / B_SPR, c4 = (slot % B_SPR) * 4;
        pb[i] = *(const float4*)(W + (size_t)krow * N + bn + c4);
    }
    #pragma unroll
    for (int i = 0; i < A_PER; ++i) {
        int slot = i * 256 + tid;
        int row = slot / A_SPR, c4 = (slot % A_SPR) * 4;
        As[c4 + 0][row] = pa[i].x;
        As[c4 + 1][row] = pa[i].y;
        As[c4 + 2][row] = pa[i].z;
        As[c4 + 3][row] = pa[i].w;
    }
    #pragma unroll
    for (int i = 0; i < B_PER; ++i) {
        int slot = i * 256 + tid;
        int krow = slot / B_SPR, c4 = (slot % B_SPR) * 4;
        *(float4*)(&Bs[krow][c4]) = pb[i];
    }
    __syncthreads();

    for (int k0 = 0; k0 < K; k0 += BK) {
        bool more = (k0 + BK) < K;
        // ---- issue next tile's global loads early (hide under compute) ----
        if (more) {
            #pragma unroll
            for (int i = 0; i < A_PER; ++i) {
                int slot = i * 256 + tid;
                int row = slot / A_SPR, c4 = (slot % A_SPR) * 4;
                pa[i] = *(const float4*)(A + (size_t)(bm + row) * K + k0 + BK + c4);
            }
            #pragma unroll
            for (int i = 0; i < B_PER; ++i) {
                int slot = i * 256 + tid;
                int krow = slot / B_SPR, c4 = (slot % B_SPR) * 4;
                pb[i] = *(const float4*)(W + (size_t)(k0 + BK + krow) * N + bn + c4);
            }
        }
        // ---- compute current tile from LDS ----
        #pragma unroll
        for (int kk = 0; kk < BK; ++kk) {
            float a[TM], b[TN];
            #pragma unroll
            for (int i = 0; i < TM / 4; ++i)
                *(float4*)(&a[i * 4]) = *(const float4*)(&As[kk][ty * TM + i * 4]);
            #pragma unroll
            for (int j = 0; j < TN / 4; ++j)
                *(float4*)(&b[j * 4]) = *(const float4*)(&Bs[kk][tx * TN + j * 4]);
            #pragma unroll
            for (int i = 0; i < TM; ++i)
                #pragma unroll
                for (int j = 0; j < TN; ++j)
                    acc[i][j] += a[i] * b[j];
        }
        __syncthreads();
        // ---- write prefetched regs to LDS ----
        if (more) {
            #pragma unroll
            for (int i = 0; i < A_PER; ++i) {
                int slot = i * 256 + tid;
                int row = slot / A_SPR, c4 = (slot % A_SPR) * 4;
                As[c4 + 0][row] = pa[i].x;
                As[c4 + 1][row] = pa[i].y;
                As[c4 + 2][row] = pa[i].z;
                As[c4 + 3][row] = pa[i].w;
            }
            #pragma unroll
            for (int i = 0; i < B_PER; ++i) {
                int slot = i * 256 + tid;
                int krow = slot / B_SPR, c4 = (slot % B_SPR) * 4;
                *(float4*)(&Bs[krow][c4]) = pb[i];
            }
            __syncthreads();
        }
    }

    // ---- epilogue: float4-vectorized along n ----
    #pragma unroll
    for (int j4 = 0; j4 < TN / 4; ++j4) {
        int ncol = bn + tx * TN + j4 * 4;
        float4 bia = *(const float4*)(bias + ncol);
        #pragma unroll
        for (int i = 0; i < TM; ++i) {
            int m = bm + ty * TM + i;
            float4 o;
            o.x = acc[i][j4 * 4 + 0] + bia.x;
            o.y = acc[i][j4 * 4 + 1] + bia.y;
            o.z = acc[i][j4 * 4 + 2] + bia.z;
            o.w = acc[i][j4 * 4 + 3] + bia.w;
            if (EPI == 1) {
                float4 r = *(const float4*)(res + (size_t)m * N + ncol);
                o.x += r.x; o.y += r.y; o.z += r.z; o.w += r.w;
            }
            if (EPI == 2) {
                o.x = 0.5f * o.x * (1.0f + erff(o.x * 0.70710678118f));
                o.y = 0.5f * o.y * (1.0f + erff(o.y * 0.70710678118f));
                o.z = 0.5f * o.z * (1.0f + erff(o.z * 0.70710678118f));
                o.w = 0.5f * o.w * (1.0f + erff(o.w * 0.70710678118f));
            }
            *(float4*)(C + (size_t)m * N + ncol) = o;
        }
    }
}

template<int BM, int BN, int TM, int TN, int EPI>
__global__ __launch_bounds__(256) void sgemm_kernel(
    const float* __restrict__ A, const float* __restrict__ W,
    const float* __restrict__ bias, const float* __restrict__ res,
    float* __restrict__ C, int M, int N, int K)
{
    gemm_body<BM, BN, TM, TN, EPI>(A, W, bias, res, C, M, N, K,
                                   blockIdx.y * BM, blockIdx.x * BN);
}

// QKV: one launch, blockIdx.z selects among {q,k,v} weight/bias/output
__global__ __launch_bounds__(256) void qkv_kernel(
    const float* __restrict__ A,
    const float* __restrict__ Wq, const float* __restrict__ bq, float* __restrict__ qo,
    const float* __restrict__ Wk, const float* __restrict__ bk, float* __restrict__ ko,
    const float* __restrict__ Wv, const float* __restrict__ bv, float* __restrict__ vo)
{
    const float* W = (blockIdx.z == 0) ? Wq : (blockIdx.z == 1) ? Wk : Wv;
    const float* b = (blockIdx.z == 0) ? bq : (blockIdx.z == 1) ? bk : bv;
    float* C       = (blockIdx.z == 0) ? qo : (blockIdx.z == 1) ? ko : vo;
    gemm_body<64, 64, 4, 4, 0>(A, W, b, nullptr, C, kRows, kD, kD,
                               blockIdx.y * 64, blockIdx.x * 64);
}

// ---------------------------------------------------------------------------
// Fused causal attention: one 256-thread block per (b, h, q-row).
// Scores in LDS, softmax in LDS, PV accumulate with 4-way k-slicing.
// q,k,v layout: (B*T, D) rows; head h occupies cols [h*64, h*64+64).
// ---------------------------------------------------------------------------
__global__ __launch_bounds__(256) void attn_kernel(
    const float* __restrict__ q, const float* __restrict__ k,
    const float* __restrict__ v, float* __restrict__ y)
{
    int idx = blockIdx.x;               // ((b*H + h)*T + t)
    int t = idx % kT;
    int h = (idx / kT) % kH;
    int b = idx / (kT * kH);
    int tid = threadIdx.x;

    __shared__ float qs[kDH];
    __shared__ float sc[kT];
    __shared__ float part[4][kDH];
    __shared__ float redbuf[4];
    __shared__ float redbuf2[4];

    const float* qrow = q + (size_t)(b * kT + t) * kD + h * kDH;
    if (tid < kDH) qs[tid] = qrow[tid];
    __syncthreads();

    int nk = t + 1;
    const float* kbase = k + (size_t)b * kT * kD + h * kDH;

    // scores
    for (int kk = tid; kk < nk; kk += 256) {
        const float4* kr = (const float4*)(kbase + (size_t)kk * kD);
        float dot = 0.0f;
        #pragma unroll
        for (int d4 = 0; d4 < kDH / 4; ++d4) {
            float4 kv = kr[d4];
            dot += kv.x * qs[d4 * 4 + 0] + kv.y * qs[d4 * 4 + 1] +
                   kv.z * qs[d4 * 4 + 2] + kv.w * qs[d4 * 4 + 3];
        }
        sc[kk] = dot * 0.125f;          // 1/sqrt(64)
    }
    __syncthreads();

    // softmax max
    float m = -INFINITY;
    for (int kk = tid; kk < nk; kk += 256) m = fmaxf(m, sc[kk]);
    #pragma unroll
    for (int off = 32; off > 0; off >>= 1) m = fmaxf(m, __shfl_down(m, off));
    if ((tid & 63) == 0) redbuf[tid >> 6] = m;
    __syncthreads();
    m = fmaxf(fmaxf(redbuf[0], redbuf[1]), fmaxf(redbuf[2], redbuf[3]));

    // exp + sum
    float ssum = 0.0f;
    for (int kk = tid; kk < nk; kk += 256) {
        float e = expf(sc[kk] - m);
        sc[kk] = e;
        ssum += e;
    }
    #pragma unroll
    for (int off = 32; off > 0; off >>= 1) ssum += __shfl_down(ssum, off);
    if ((tid & 63) == 0) redbuf2[tid >> 6] = ssum;
    __syncthreads();                    // also publishes sc[] exp values
    float inv = 1.0f / (redbuf2[0] + redbuf2[1] + redbuf2[2] + redbuf2[3]);

    // PV: d = tid%64, 4-way slice over k
    int d = tid & 63;
    int slice = tid >> 6;
    const float* vbase = v + (size_t)b * kT * kD + h * kDH + d;
    float accp = 0.0f;
    for (int kk = slice; kk < nk; kk += 4)
        accp += sc[kk] * vbase[(size_t)kk * kD];
    part[slice][d] = accp;
    __syncthreads();
    if (tid < kDH) {
        float r = (part[0][tid] + part[1][tid] + part[2][tid] + part[3][tid]) * inv;
        y[(size_t)(b * kT + t) * kD + h * kDH + tid] = r;
    }
}

// ---------------------------------------------------------------------------
// Host-side launch
// ---------------------------------------------------------------------------
extern "C" void kernel_launch(void* const* d_in, const int* in_sizes, int n_in,
                              void* d_out, int out_size, void* d_ws, size_t ws_size,
                              hipStream_t stream)
{
    const int*   tokens = (const int*)  d_in[0];
    const float* emb    = (const float*)d_in[1];
    const float* pos    = (const float*)d_in[2];
    const float* ln1_s  = (const float*)d_in[3];
    const float* ln1_b  = (const float*)d_in[4];
    const float* Wq     = (const float*)d_in[5];
    const float* bq     = (const float*)d_in[6];
    const float* Wk     = (const float*)d_in[7];
    const float* bk     = (const float*)d_in[8];
    const float* Wv     = (const float*)d_in[9];
    const float* bv     = (const float*)d_in[10];
    const float* Wo     = (const float*)d_in[11];
    const float* bo     = (const float*)d_in[12];
    const float* ln2_s  = (const float*)d_in[13];
    const float* ln2_b  = (const float*)d_in[14];
    const float* W1     = (const float*)d_in[15];
    const float* b1     = (const float*)d_in[16];
    const float* W2     = (const float*)d_in[17];
    const float* b2     = (const float*)d_in[18];
    const float* lnf_s  = (const float*)d_in[19];
    const float* lnf_b  = (const float*)d_in[20];
    const float* Wl     = (const float*)d_in[21];
    const float* bl     = (const float*)d_in[22];
    float* out = (float*)d_out;

    size_t BTD = (size_t)kRows * kD;    // 2,097,152 floats
    float* ws  = (float*)d_ws;
    float* x   = ws;                    // residual stream
    float* h   = x + BTD;               // LN output / attn out (reused)
    float* qb  = h + BTD;
    float* kb  = qb + BTD;
    float* vb  = kb + BTD;
    float* mid = qb;                    // FFN mid (4*BTD) ALIASES qb..vb+1:
                                        // q/k/v are dead after attn_kernel,
                                        // mid is written after (ln2 -> ffn1).
    // total ws: 6*BTD*4B = 50.3 MB

    embed_kernel<<<kRows, 256, 0, stream>>>(tokens, emb, pos, x);

    dim3 gQkv(kD / 64, kRows / 64, 3);        // 16 x 32 x 3
    dim3 gProj(kD / 64, kRows / 64);          // 16 x 32  (64x64 tiles)
    dim3 gFfn1(4 * kD / 128, kRows / 128);    // 32 x 16  (128x128 tiles)
    dim3 gLogit(kV / 128, kRows / 128);       // 250 x 16 (128x128 tiles)

    for (int i = 0; i < kL; ++i) {
        size_t oD  = (size_t)i * kD;
        size_t oDD = (size_t)i * kD * kD;
        size_t oD4 = (size_t)i * 4 * kD;
        size_t oDD4 = (size_t)i * kD * 4 * kD;

        ln_kernel<<<kRows, 256, 0, stream>>>(x, ln1_s + oD, ln1_b + oD, h);

        qkv_kernel<<<gQkv, 256, 0, stream>>>(h,
            Wq + oDD, bq + oD, qb,
            Wk + oDD, bk + oD, kb,
            Wv + oDD, bv + oD, vb);

        attn_kernel<<<kB * kH * kT, 256, 0, stream>>>(qb, kb, vb, h);

        sgemm_kernel<64, 64, 4, 4, 1><<<gProj, 256, 0, stream>>>(h, Wo + oDD, bo + oD, x, x, kRows, kD, kD);

        ln_kernel<<<kRows, 256, 0, stream>>>(x, ln2_s + oD, ln2_b + oD, h);

        sgemm_kernel<128, 128, 8, 8, 2><<<gFfn1, 256, 0, stream>>>(h, W1 + oDD4, b1 + oD4, nullptr, mid, kRows, 4 * kD, kD);
        sgemm_kernel<64, 64, 4, 4, 1><<<gProj, 256, 0, stream>>>(mid, W2 + oDD4, b2 + oD, x, x, kRows, kD, 4 * kD);
    }

    ln_kernel<<<kRows, 256, 0, stream>>>(x, lnf_s, lnf_b, h);
    sgemm_kernel<128, 128, 8, 8, 0><<<gLogit, 256, 0, stream>>>(h, Wl, bl, nullptr, out, kRows, kV, kD);
}

// Round 5
// 10605.834 us; speedup vs baseline: 1.4464x; 1.4464x over previous
//
#include <hip/hip_runtime.h>
#include <hip/hip_bf16.h>
#include <math.h>

// Problem constants (match reference)
constexpr int kD = 1024;
constexpr int kH = 16;
constexpr int kDH = 64;     // head dim
constexpr int kV = 32000;
constexpr int kL = 8;
constexpr int kB = 2;
constexpr int kT = 1024;
constexpr int kRows = kB * kT;          // 2048 token rows
constexpr float kEPS = 1e-5f;

typedef __attribute__((ext_vector_type(8))) short short8v;  // 8 bf16 (4 VGPR)
typedef __attribute__((ext_vector_type(4))) float f32x4;

// fp32 -> bf16 (round-to-nearest-even), packed pair into one dword
__device__ __forceinline__ uint32_t pk2(float a, float b) {
    union { float f; uint32_t u; } x, y;
    x.f = a; y.f = b;
    uint32_t lo = (x.u + 0x7FFFu + ((x.u >> 16) & 1)) >> 16;
    uint32_t hi = (y.u + 0x7FFFu + ((y.u >> 16) & 1)) >> 16;
    return lo | (hi << 16);
}

// Swizzled 16B-slot index for k-major LDS tiles: idx in [0,BM), kg in [0,4)
// Uniform bank spread for wave-wide ds_read_b128 (8 accesses/bank exactly).
__device__ __forceinline__ int swz(int idx, int kg) {
    return idx * 4 + (kg ^ ((idx ^ (idx >> 2)) & 3));
}

// ---------------------------------------------------------------------------
// Embedding: x[b,t,:] = emb[tokens[b,t],:] + pos_emb[t,:]
// ---------------------------------------------------------------------------
__global__ __launch_bounds__(256) void embed_kernel(
    const int* __restrict__ tokens, const float* __restrict__ emb,
    const float* __restrict__ pos, float* __restrict__ x)
{
    int row = blockIdx.x;               // b*T + t
    int t = row % kT;
    int tok = tokens[row];
    const float4* e = (const float4*)(emb + (size_t)tok * kD);
    const float4* p = (const float4*)(pos + (size_t)t * kD);
    float4* o = (float4*)(x + (size_t)row * kD);
    int i = threadIdx.x;                // 256 threads x float4 = 1024 floats
    float4 a = e[i], b4 = p[i];
    o[i] = make_float4(a.x + b4.x, a.y + b4.y, a.z + b4.z, a.w + b4.w);
}

// ---------------------------------------------------------------------------
// LayerNorm: one 256-thread block per row of D=1024
// ---------------------------------------------------------------------------
__global__ __launch_bounds__(256) void ln_kernel(
    const float* __restrict__ x, const float* __restrict__ sc,
    const float* __restrict__ bi, float* __restrict__ out)
{
    int row = blockIdx.x;
    int tid = threadIdx.x;
    float4 v4 = ((const float4*)(x + (size_t)row * kD))[tid];

    __shared__ float red1[4];
    __shared__ float red2[4];

    float s = v4.x + v4.y + v4.z + v4.w;
    #pragma unroll
    for (int off = 32; off > 0; off >>= 1) s += __shfl_down(s, off);
    if ((tid & 63) == 0) red1[tid >> 6] = s;
    __syncthreads();
    float mean = (red1[0] + red1[1] + red1[2] + red1[3]) * (1.0f / kD);

    float dx = v4.x - mean, dy = v4.y - mean, dz = v4.z - mean, dw = v4.w - mean;
    float vs = dx * dx + dy * dy + dz * dz + dw * dw;
    #pragma unroll
    for (int off = 32; off > 0; off >>= 1) vs += __shfl_down(vs, off);
    if ((tid & 63) == 0) red2[tid >> 6] = vs;
    __syncthreads();
    float var = (red2[0] + red2[1] + red2[2] + red2[3]) * (1.0f / kD);
    float inv = rsqrtf(var + kEPS);

    float4 s4 = ((const float4*)sc)[tid];
    float4 b4 = ((const float4*)bi)[tid];
    float4 o;
    o.x = dx * inv * s4.x + b4.x;
    o.y = dy * inv * s4.y + b4.y;
    o.z = dz * inv * s4.z + b4.z;
    o.w = dw * inv * s4.w + b4.w;
    ((float4*)(out + (size_t)row * kD))[tid] = o;
}

// ---------------------------------------------------------------------------
// bf16 MFMA GEMM: C[M,N] = A[M,K] @ W[K,N] + bias (+ residual / gelu)
// fp32 global inputs, cast to bf16 at LDS staging, fp32 accumulate.
// 256 threads = 4 waves (2x2); wave owns (BM/2)x(BN/2); 16x16x32 fragments.
// LDS: k-major swizzled tiles, conflict-free ds_read_b128 fragments.
// EPI: 0 = bias, 1 = bias + residual, 2 = bias + exact GELU
// ---------------------------------------------------------------------------
template<int BM, int BN, int EPI>
__device__ __forceinline__ void mgemm_body(
    const float* __restrict__ A, const float* __restrict__ W,
    const float* __restrict__ bias, const float* __restrict__ res,
    float* __restrict__ C, int N, int K, int bm, int bn)
{
    constexpr int KSTEP = 32;
    constexpr int FM = (BM / 2) / 16;           // fragment rows per wave
    constexpr int FN = (BN / 2) / 16;           // fragment cols per wave
    constexpr int A_PER = (BM * 4) / 256;       // A 16B-slots per thread
    constexpr int KPT = BN / 32;                // B k-rows per thread
    constexpr int NMASK = BN / 4 - 1;
    constexpr int KQSH = (BN == 128) ? 5 : 4;

    __shared__ uint4 smem[BM * 4 + BN * 4];     // 16B slots: A then B
    char* sA = (char*)smem;
    char* sB = (char*)(smem + BM * 4);

    int tid = threadIdx.x;
    int lane = tid & 63;
    int wv = tid >> 6;
    int wr = wv >> 1, wc = wv & 1;
    int fr = lane & 15;                          // fragment row/col index
    int kg = lane >> 4;                          // k-group 0..3

    int n4 = tid & NMASK;                        // B staging: col group
    int kq = tid >> KQSH;
    int kbase = kq * KPT;

    f32x4 acc[FM][FN] = {};
    float4 pa[A_PER][2];
    float4 pb[KPT];

    auto loadA = [&](int k0) {
        #pragma unroll
        for (int s = 0; s < A_PER; ++s) {
            int slot = tid * A_PER + s;
            int row = slot >> 2, k8 = slot & 3;
            const float* p = A + (size_t)(bm + row) * K + k0 + k8 * 8;
            pa[s][0] = *(const float4*)p;
            pa[s][1] = *(const float4*)(p + 4);
        }
    };
    auto loadB = [&](int k0) {
        #pragma unroll
        for (int i = 0; i < KPT; ++i)
            pb[i] = *(const float4*)(W + (size_t)(k0 + kbase + i) * N + bn + n4 * 4);
    };
    auto writeA = [&]() {
        #pragma unroll
        for (int s = 0; s < A_PER; ++s) {
            int slot = tid * A_PER + s;
            int row = slot >> 2, k8 = slot & 3;
            uint4 w;
            w.x = pk2(pa[s][0].x, pa[s][0].y);
            w.y = pk2(pa[s][0].z, pa[s][0].w);
            w.z = pk2(pa[s][1].x, pa[s][1].y);
            w.w = pk2(pa[s][1].z, pa[s][1].w);
            *(uint4*)(sA + swz(row, k8) * 16) = w;
        }
    };
    auto writeB = [&]() {
        int kgc = kbase >> 3;
        int kb8 = (kbase & 7) * 2;
        #pragma unroll
        for (int j = 0; j < 4; ++j) {
            int col = n4 * 4 + j;
            char* dst = sB + swz(col, kgc) * 16 + kb8;
            if constexpr (KPT == 4) {
                uint2 w;
                w.x = pk2((&pb[0].x)[j], (&pb[1].x)[j]);
                w.y = pk2((&pb[2].x)[j], (&pb[3].x)[j]);
                *(uint2*)dst = w;
            } else {
                *(uint32_t*)dst = pk2((&pb[0].x)[j], (&pb[1].x)[j]);
            }
        }
    };
    auto compute = [&]() {
        short8v af[FM], bf[FN];
        #pragma unroll
        for (int mi = 0; mi < FM; ++mi) {
            int row = wr * (BM / 2) + mi * 16 + fr;
            af[mi] = *(const short8v*)(sA + swz(row, kg) * 16);
        }
        #pragma unroll
        for (int nj = 0; nj < FN; ++nj) {
            int col = wc * (BN / 2) + nj * 16 + fr;
            bf[nj] = *(const short8v*)(sB + swz(col, kg) * 16);
        }
        #pragma unroll
        for (int mi = 0; mi < FM; ++mi)
            #pragma unroll
            for (int nj = 0; nj < FN; ++nj)
                acc[mi][nj] = __builtin_amdgcn_mfma_f32_16x16x32_bf16(
                    af[mi], bf[nj], acc[mi][nj], 0, 0, 0);
    };

    // prologue
    loadA(0); loadB(0);
    writeA(); writeB();
    __syncthreads();

    for (int k0 = 0; k0 < K; k0 += KSTEP) {
        bool more = (k0 + KSTEP) < K;
        if (more) { loadA(k0 + KSTEP); loadB(k0 + KSTEP); }  // hide under MFMA
        compute();
        __syncthreads();
        if (more) {
            writeA(); writeB();
            __syncthreads();
        }
    }

    // epilogue: C/D layout col=lane&15, row=(lane>>4)*4+r  [m89-verified]
    #pragma unroll
    for (int mi = 0; mi < FM; ++mi) {
        #pragma unroll
        for (int nj = 0; nj < FN; ++nj) {
            int col = bn + wc * (BN / 2) + nj * 16 + fr;
            float bia = bias[col];
            #pragma unroll
            for (int r = 0; r < 4; ++r) {
                int row = bm + wr * (BM / 2) + mi * 16 + kg * 4 + r;
                float o = acc[mi][nj][r] + bia;
                if (EPI == 1) o += res[(size_t)row * N + col];
                if (EPI == 2) o = 0.5f * o * (1.0f + erff(o * 0.70710678118f));
                C[(size_t)row * N + col] = o;
            }
        }
    }
}

template<int BM, int BN, int EPI>
__global__ __launch_bounds__(256) void mgemm_kernel(
    const float* __restrict__ A, const float* __restrict__ W,
    const float* __restrict__ bias, const float* __restrict__ res,
    float* __restrict__ C, int N, int K)
{
    mgemm_body<BM, BN, EPI>(A, W, bias, res, C, N, K,
                            blockIdx.y * BM, blockIdx.x * BN);
}

// QKV: one launch, blockIdx.z selects among {q,k,v} weight/bias/output
__global__ __launch_bounds__(256) void mgemm_qkv_kernel(
    const float* __restrict__ A,
    const float* __restrict__ Wq, const float* __restrict__ bq, float* __restrict__ qo,
    const float* __restrict__ Wk, const float* __restrict__ bk, float* __restrict__ ko,
    const float* __restrict__ Wv, const float* __restrict__ bv, float* __restrict__ vo)
{
    const float* W = (blockIdx.z == 0) ? Wq : (blockIdx.z == 1) ? Wk : Wv;
    const float* b = (blockIdx.z == 0) ? bq : (blockIdx.z == 1) ? bk : bv;
    float* C       = (blockIdx.z == 0) ? qo : (blockIdx.z == 1) ? ko : vo;
    mgemm_body<128, 64, 0>(A, W, b, nullptr, C, kD, kD,
                           blockIdx.y * 128, blockIdx.x * 64);
}

// ---------------------------------------------------------------------------
// Fused causal attention: one 256-thread block per (b, h, q-row). (unchanged)
// ---------------------------------------------------------------------------
__global__ __launch_bounds__(256) void attn_kernel(
    const float* __restrict__ q, const float* __restrict__ k,
    const float* __restrict__ v, float* __restrict__ y)
{
    int idx = blockIdx.x;               // ((b*H + h)*T + t)
    int t = idx % kT;
    int h = (idx / kT) % kH;
    int b = idx / (kT * kH);
    int tid = threadIdx.x;

    __shared__ float qs[kDH];
    __shared__ float sc[kT];
    __shared__ float part[4][kDH];
    __shared__ float redbuf[4];
    __shared__ float redbuf2[4];

    const float* qrow = q + (size_t)(b * kT + t) * kD + h * kDH;
    if (tid < kDH) qs[tid] = qrow[tid];
    __syncthreads();

    int nk = t + 1;
    const float* kbase = k + (size_t)b * kT * kD + h * kDH;

    // scores
    for (int kk = tid; kk < nk; kk += 256) {
        const float4* kr = (const float4*)(kbase + (size_t)kk * kD);
        float dot = 0.0f;
        #pragma unroll
        for (int d4 = 0; d4 < kDH / 4; ++d4) {
            float4 kv = kr[d4];
            dot += kv.x * qs[d4 * 4 + 0] + kv.y * qs[d4 * 4 + 1] +
                   kv.z * qs[d4 * 4 + 2] + kv.w * qs[d4 * 4 + 3];
        }
        sc[kk] = dot * 0.125f;          // 1/sqrt(64)
    }
    __syncthreads();

    // softmax max
    float m = -INFINITY;
    for (int kk = tid; kk < nk; kk += 256) m = fmaxf(m, sc[kk]);
    #pragma unroll
    for (int off = 32; off > 0; off >>= 1) m = fmaxf(m, __shfl_down(m, off));
    if ((tid & 63) == 0) redbuf[tid >> 6] = m;
    __syncthreads();
    m = fmaxf(fmaxf(redbuf[0], redbuf[1]), fmaxf(redbuf[2], redbuf[3]));

    // exp + sum
    float ssum = 0.0f;
    for (int kk = tid; kk < nk; kk += 256) {
        float e = expf(sc[kk] - m);
        sc[kk] = e;
        ssum += e;
    }
    #pragma unroll
    for (int off = 32; off > 0; off >>= 1) ssum += __shfl_down(ssum, off);
    if ((tid & 63) == 0) redbuf2[tid >> 6] = ssum;
    __syncthreads();                    // also publishes sc[] exp values
    float inv = 1.0f / (redbuf2[0] + redbuf2[1] + redbuf2[2] + redbuf2[3]);

    // PV: d = tid%64, 4-way slice over k
    int d = tid & 63;
    int slice = tid >> 6;
    const float* vbase = v + (size_t)b * kT * kD + h * kDH + d;
    float accp = 0.0f;
    for (int kk = slice; kk < nk; kk += 4)
        accp += sc[kk] * vbase[(size_t)kk * kD];
    part[slice][d] = accp;
    __syncthreads();
    if (tid < kDH) {
        float r = (part[0][tid] + part[1][tid] + part[2][tid] + part[3][tid]) * inv;
        y[(size_t)(b * kT + t) * kD + h * kDH + tid] = r;
    }
}

// ---------------------------------------------------------------------------
// Host-side launch
// ---------------------------------------------------------------------------
extern "C" void kernel_launch(void* const* d_in, const int* in_sizes, int n_in,
                              void* d_out, int out_size, void* d_ws, size_t ws_size,
                              hipStream_t stream)
{
    const int*   tokens = (const int*)  d_in[0];
    const float* emb    = (const float*)d_in[1];
    const float* pos    = (const float*)d_in[2];
    const float* ln1_s  = (const float*)d_in[3];
    const float* ln1_b  = (const float*)d_in[4];
    const float* Wq     = (const float*)d_in[5];
    const float* bq     = (const float*)d_in[6];
    const float* Wk     = (const float*)d_in[7];
    const float* bk     = (const float*)d_in[8];
    const float* Wv     = (const float*)d_in[9];
    const float* bv     = (const float*)d_in[10];
    const float* Wo     = (const float*)d_in[11];
    const float* bo     = (const float*)d_in[12];
    const float* ln2_s  = (const float*)d_in[13];
    const float* ln2_b  = (const float*)d_in[14];
    const float* W1     = (const float*)d_in[15];
    const float* b1     = (const float*)d_in[16];
    const float* W2     = (const float*)d_in[17];
    const float* b2     = (const float*)d_in[18];
    const float* lnf_s  = (const float*)d_in[19];
    const float* lnf_b  = (const float*)d_in[20];
    const float* Wl     = (const float*)d_in[21];
    const float* bl     = (const float*)d_in[22];
    float* out = (float*)d_out;

    size_t BTD = (size_t)kRows * kD;    // 2,097,152 floats
    float* ws  = (float*)d_ws;
    float* x   = ws;                    // residual stream
    float* h   = x + BTD;               // LN output / attn out (reused)
    float* qb  = h + BTD;
    float* kb  = qb + BTD;
    float* vb  = kb + BTD;
    float* mid = qb;                    // FFN mid (4*BTD) aliases qb..vb
    // total ws: 6*BTD*4B = 50.3 MB

    embed_kernel<<<kRows, 256, 0, stream>>>(tokens, emb, pos, x);

    dim3 gQkv(kD / 64, kRows / 128, 3);       // 16 x 16 x 3 (128x64 tiles)
    dim3 gProj(kD / 64, kRows / 128);         // 16 x 16    (128x64 tiles)
    dim3 gFfn1(4 * kD / 128, kRows / 128);    // 32 x 16    (128x128 tiles)
    dim3 gLogit(kV / 128, kRows / 128);       // 250 x 16   (128x128 tiles)

    for (int i = 0; i < kL; ++i) {
        size_t oD  = (size_t)i * kD;
        size_t oDD = (size_t)i * kD * kD;
        size_t oD4 = (size_t)i * 4 * kD;
        size_t oDD4 = (size_t)i * kD * 4 * kD;

        ln_kernel<<<kRows, 256, 0, stream>>>(x, ln1_s + oD, ln1_b + oD, h);

        mgemm_qkv_kernel<<<gQkv, 256, 0, stream>>>(h,
            Wq + oDD, bq + oD, qb,
            Wk + oDD, bk + oD, kb,
            Wv + oDD, bv + oD, vb);

        attn_kernel<<<kB * kH * kT, 256, 0, stream>>>(qb, kb, vb, h);

        mgemm_kernel<128, 64, 1><<<gProj, 256, 0, stream>>>(h, Wo + oDD, bo + oD, x, x, kD, kD);

        ln_kernel<<<kRows, 256, 0, stream>>>(x, ln2_s + oD, ln2_b + oD, h);

        mgemm_kernel<128, 128, 2><<<gFfn1, 256, 0, stream>>>(h, W1 + oDD4, b1 + oD4, nullptr, mid, 4 * kD, kD);
        mgemm_kernel<128, 64, 1><<<gProj, 256, 0, stream>>>(mid, W2 + oDD4, b2 + oD, x, x, kD, 4 * kD);
    }

    ln_kernel<<<kRows, 256, 0, stream>>>(x, lnf_s, lnf_b, h);
    mgemm_kernel<128, 128, 0><<<gLogit, 256, 0, stream>>>(h, Wl, bl, nullptr, out, kV, kD);
}

// Round 6
// 3741.650 us; speedup vs baseline: 4.0999x; 2.8345x over previous
//
#include <hip/hip_runtime.h>
#include <hip/hip_bf16.h>
#include <math.h>

// Problem constants (match reference)
constexpr int kD = 1024;
constexpr int kH = 16;
constexpr int kDH = 64;     // head dim
constexpr int kV = 32000;
constexpr int kL = 8;
constexpr int kB = 2;
constexpr int kT = 1024;
constexpr int kRows = kB * kT;          // 2048 token rows
constexpr float kEPS = 1e-5f;

typedef __attribute__((ext_vector_type(8))) short short8v;  // 8 bf16 (4 VGPR)
typedef __attribute__((ext_vector_type(4))) float f32x4;

// fp32 -> bf16 (round-to-nearest-even), packed pair into one dword
__device__ __forceinline__ uint32_t pk2(float a, float b) {
    union { float f; uint32_t u; } x, y;
    x.f = a; y.f = b;
    uint32_t lo = (x.u + 0x7FFFu + ((x.u >> 16) & 1)) >> 16;
    uint32_t hi = (y.u + 0x7FFFu + ((y.u >> 16) & 1)) >> 16;
    return lo | (hi << 16);
}
__device__ __forceinline__ unsigned short bf1(float a) {
    union { float f; uint32_t u; } x; x.f = a;
    return (unsigned short)((x.u + 0x7FFFu + ((x.u >> 16) & 1)) >> 16);
}

// Swizzled 16B-slot index for k-major LDS tiles: idx in [0,BM), kg in [0,4)
__device__ __forceinline__ int swz(int idx, int kg) {
    return idx * 4 + (kg ^ ((idx ^ (idx >> 2)) & 3));
}

// ---------------------------------------------------------------------------
// Embedding
// ---------------------------------------------------------------------------
__global__ __launch_bounds__(256) void embed_kernel(
    const int* __restrict__ tokens, const float* __restrict__ emb,
    const float* __restrict__ pos, float* __restrict__ x)
{
    int row = blockIdx.x;               // b*T + t
    int t = row % kT;
    int tok = tokens[row];
    const float4* e = (const float4*)(emb + (size_t)tok * kD);
    const float4* p = (const float4*)(pos + (size_t)t * kD);
    float4* o = (float4*)(x + (size_t)row * kD);
    int i = threadIdx.x;
    float4 a = e[i], b4 = p[i];
    o[i] = make_float4(a.x + b4.x, a.y + b4.y, a.z + b4.z, a.w + b4.w);
}

// ---------------------------------------------------------------------------
// LayerNorm: one 256-thread block per row of D=1024
// ---------------------------------------------------------------------------
__global__ __launch_bounds__(256) void ln_kernel(
    const float* __restrict__ x, const float* __restrict__ sc,
    const float* __restrict__ bi, float* __restrict__ out)
{
    int row = blockIdx.x;
    int tid = threadIdx.x;
    float4 v4 = ((const float4*)(x + (size_t)row * kD))[tid];

    __shared__ float red1[4];
    __shared__ float red2[4];

    float s = v4.x + v4.y + v4.z + v4.w;
    #pragma unroll
    for (int off = 32; off > 0; off >>= 1) s += __shfl_down(s, off);
    if ((tid & 63) == 0) red1[tid >> 6] = s;
    __syncthreads();
    float mean = (red1[0] + red1[1] + red1[2] + red1[3]) * (1.0f / kD);

    float dx = v4.x - mean, dy = v4.y - mean, dz = v4.z - mean, dw = v4.w - mean;
    float vs = dx * dx + dy * dy + dz * dz + dw * dw;
    #pragma unroll
    for (int off = 32; off > 0; off >>= 1) vs += __shfl_down(vs, off);
    if ((tid & 63) == 0) red2[tid >> 6] = vs;
    __syncthreads();
    float var = (red2[0] + red2[1] + red2[2] + red2[3]) * (1.0f / kD);
    float inv = rsqrtf(var + kEPS);

    float4 s4 = ((const float4*)sc)[tid];
    float4 b4 = ((const float4*)bi)[tid];
    float4 o;
    o.x = dx * inv * s4.x + b4.x;
    o.y = dy * inv * s4.y + b4.y;
    o.z = dz * inv * s4.z + b4.z;
    o.w = dw * inv * s4.w + b4.w;
    ((float4*)(out + (size_t)row * kD))[tid] = o;
}

// ---------------------------------------------------------------------------
// bf16 MFMA GEMM (validated round 5) — unchanged
// ---------------------------------------------------------------------------
template<int BM, int BN, int EPI>
__device__ __forceinline__ void mgemm_body(
    const float* __restrict__ A, const float* __restrict__ W,
    const float* __restrict__ bias, const float* __restrict__ res,
    float* __restrict__ C, int N, int K, int bm, int bn)
{
    constexpr int KSTEP = 32;
    constexpr int FM = (BM / 2) / 16;
    constexpr int FN = (BN / 2) / 16;
    constexpr int A_PER = (BM * 4) / 256;
    constexpr int KPT = BN / 32;
    constexpr int NMASK = BN / 4 - 1;
    constexpr int KQSH = (BN == 128) ? 5 : 4;

    __shared__ uint4 smem[BM * 4 + BN * 4];
    char* sA = (char*)smem;
    char* sB = (char*)(smem + BM * 4);

    int tid = threadIdx.x;
    int lane = tid & 63;
    int wv = tid >> 6;
    int wr = wv >> 1, wc = wv & 1;
    int fr = lane & 15;
    int kg = lane >> 4;

    int n4 = tid & NMASK;
    int kq = tid >> KQSH;
    int kbase = kq * KPT;

    f32x4 acc[FM][FN] = {};
    float4 pa[A_PER][2];
    float4 pb[KPT];

    auto loadA = [&](int k0) {
        #pragma unroll
        for (int s = 0; s < A_PER; ++s) {
            int slot = tid * A_PER + s;
            int row = slot >> 2, k8 = slot & 3;
            const float* p = A + (size_t)(bm + row) * K + k0 + k8 * 8;
            pa[s][0] = *(const float4*)p;
            pa[s][1] = *(const float4*)(p + 4);
        }
    };
    auto loadB = [&](int k0) {
        #pragma unroll
        for (int i = 0; i < KPT; ++i)
            pb[i] = *(const float4*)(W + (size_t)(k0 + kbase + i) * N + bn + n4 * 4);
    };
    auto writeA = [&]() {
        #pragma unroll
        for (int s = 0; s < A_PER; ++s) {
            int slot = tid * A_PER + s;
            int row = slot >> 2, k8 = slot & 3;
            uint4 w;
            w.x = pk2(pa[s][0].x, pa[s][0].y);
            w.y = pk2(pa[s][0].z, pa[s][0].w);
            w.z = pk2(pa[s][1].x, pa[s][1].y);
            w.w = pk2(pa[s][1].z, pa[s][1].w);
            *(uint4*)(sA + swz(row, k8) * 16) = w;
        }
    };
    auto writeB = [&]() {
        int kgc = kbase >> 3;
        int kb8 = (kbase & 7) * 2;
        #pragma unroll
        for (int j = 0; j < 4; ++j) {
            int col = n4 * 4 + j;
            char* dst = sB + swz(col, kgc) * 16 + kb8;
            if constexpr (KPT == 4) {
                uint2 w;
                w.x = pk2((&pb[0].x)[j], (&pb[1].x)[j]);
                w.y = pk2((&pb[2].x)[j], (&pb[3].x)[j]);
                *(uint2*)dst = w;
            } else {
                *(uint32_t*)dst = pk2((&pb[0].x)[j], (&pb[1].x)[j]);
            }
        }
    };
    auto compute = [&]() {
        short8v af[FM], bf[FN];
        #pragma unroll
        for (int mi = 0; mi < FM; ++mi) {
            int row = wr * (BM / 2) + mi * 16 + fr;
            af[mi] = *(const short8v*)(sA + swz(row, kg) * 16);
        }
        #pragma unroll
        for (int nj = 0; nj < FN; ++nj) {
            int col = wc * (BN / 2) + nj * 16 + fr;
            bf[nj] = *(const short8v*)(sB + swz(col, kg) * 16);
        }
        #pragma unroll
        for (int mi = 0; mi < FM; ++mi)
            #pragma unroll
            for (int nj = 0; nj < FN; ++nj)
                acc[mi][nj] = __builtin_amdgcn_mfma_f32_16x16x32_bf16(
                    af[mi], bf[nj], acc[mi][nj], 0, 0, 0);
    };

    loadA(0); loadB(0);
    writeA(); writeB();
    __syncthreads();

    for (int k0 = 0; k0 < K; k0 += KSTEP) {
        bool more = (k0 + KSTEP) < K;
        if (more) { loadA(k0 + KSTEP); loadB(k0 + KSTEP); }
        compute();
        __syncthreads();
        if (more) {
            writeA(); writeB();
            __syncthreads();
        }
    }

    #pragma unroll
    for (int mi = 0; mi < FM; ++mi) {
        #pragma unroll
        for (int nj = 0; nj < FN; ++nj) {
            int col = bn + wc * (BN / 2) + nj * 16 + fr;
            float bia = bias[col];
            #pragma unroll
            for (int r = 0; r < 4; ++r) {
                int row = bm + wr * (BM / 2) + mi * 16 + kg * 4 + r;
                float o = acc[mi][nj][r] + bia;
                if (EPI == 1) o += res[(size_t)row * N + col];
                if (EPI == 2) o = 0.5f * o * (1.0f + erff(o * 0.70710678118f));
                C[(size_t)row * N + col] = o;
            }
        }
    }
}

template<int BM, int BN, int EPI>
__global__ __launch_bounds__(256) void mgemm_kernel(
    const float* __restrict__ A, const float* __restrict__ W,
    const float* __restrict__ bias, const float* __restrict__ res,
    float* __restrict__ C, int N, int K)
{
    mgemm_body<BM, BN, EPI>(A, W, bias, res, C, N, K,
                            blockIdx.y * BM, blockIdx.x * BN);
}

__global__ __launch_bounds__(256) void mgemm_qkv_kernel(
    const float* __restrict__ A,
    const float* __restrict__ Wq, const float* __restrict__ bq, float* __restrict__ qo,
    const float* __restrict__ Wk, const float* __restrict__ bk, float* __restrict__ ko,
    const float* __restrict__ Wv, const float* __restrict__ bv, float* __restrict__ vo)
{
    const float* W = (blockIdx.z == 0) ? Wq : (blockIdx.z == 1) ? Wk : Wv;
    const float* b = (blockIdx.z == 0) ? bq : (blockIdx.z == 1) ? bk : bv;
    float* C       = (blockIdx.z == 0) ? qo : (blockIdx.z == 1) ? ko : vo;
    mgemm_body<128, 64, 0>(A, W, b, nullptr, C, kD, kD,
                           blockIdx.y * 128, blockIdx.x * 64);
}

// ---------------------------------------------------------------------------
// Flash attention, bf16 MFMA. Block = 256 thr = 4 waves; 64 q-rows per block.
// grid: (T/64, H, B); heaviest q-tiles first. KV tiles of 64.
// LDS tiles: [row][8 dg-slots of 16B], slot ^= (row&7)  (2-way max conflict).
// ---------------------------------------------------------------------------
__global__ __launch_bounds__(256) void fattn_kernel(
    const float* __restrict__ q, const float* __restrict__ k,
    const float* __restrict__ v, float* __restrict__ y)
{
    int qt = (int)(gridDim.x - 1) - (int)blockIdx.x;   // reversed: big first
    int h = blockIdx.y;
    int b = blockIdx.z;
    int q0 = qt * 64;

    __shared__ __align__(16) char sQ[8192];    // [64 q ][8 dg]
    __shared__ __align__(16) char sK[8192];    // [64 k ][8 dg]
    __shared__ __align__(16) char sVT[8192];   // [64 d ][8 kg]
    __shared__ __align__(16) char sP[4][2048]; // per-wave [16 q][8 kg]

    int tid = threadIdx.x;
    int lane = tid & 63;
    int w = tid >> 6;
    int fr = lane & 15;
    int g4 = lane >> 4;          // 0..3

    const float* qbase = q + (size_t)(b * kT) * kD + h * kDH;
    const float* kbase = k + (size_t)(b * kT) * kD + h * kDH;
    const float* vbase = v + (size_t)(b * kT) * kD + h * kDH;

    int srow = tid >> 2;         // staging: row 0..63
    int c4 = tid & 3;            // staging: d-chunk of 16

    // ---- stage Q tile, pre-scaled by 1/8 (exact pow2) ----
    {
        const float* src = qbase + (size_t)(q0 + srow) * kD + c4 * 16;
        float4 f0 = ((const float4*)src)[0];
        float4 f1 = ((const float4*)src)[1];
        float4 f2 = ((const float4*)src)[2];
        float4 f3 = ((const float4*)src)[3];
        const float s8 = 0.125f;
        uint4 w0, w1;
        w0.x = pk2(f0.x * s8, f0.y * s8); w0.y = pk2(f0.z * s8, f0.w * s8);
        w0.z = pk2(f1.x * s8, f1.y * s8); w0.w = pk2(f1.z * s8, f1.w * s8);
        w1.x = pk2(f2.x * s8, f2.y * s8); w1.y = pk2(f2.z * s8, f2.w * s8);
        w1.z = pk2(f3.x * s8, f3.y * s8); w1.w = pk2(f3.z * s8, f3.w * s8);
        *(uint4*)(sQ + srow * 128 + (((c4 * 2)     ^ (srow & 7)) * 16)) = w0;
        *(uint4*)(sQ + srow * 128 + (((c4 * 2 + 1) ^ (srow & 7)) * 16)) = w1;
    }
    __syncthreads();

    short8v aq[2];
    {
        int row = w * 16 + fr;       // (row&7)==(fr&7)
        aq[0] = *(const short8v*)(sQ + row * 128 + (((g4)     ^ (fr & 7)) * 16));
        aq[1] = *(const short8v*)(sQ + row * 128 + (((4 + g4) ^ (fr & 7)) * 16));
    }

    f32x4 accO[4] = {};              // [nj over d]; col d=nj*16+fr, row q=g4*4+r
    float mrow[4], lrow[4];
    #pragma unroll
    for (int r = 0; r < 4; ++r) { mrow[r] = -INFINITY; lrow[r] = 0.0f; }

    int ntiles = qt + 1;
    for (int t = 0; t < ntiles; ++t) {
        int k0 = t * 64;
        __syncthreads();             // prior tile's sK/sVT reads done
        // ---- stage K tile ----
        {
            const float* src = kbase + (size_t)(k0 + srow) * kD + c4 * 16;
            float4 f0 = ((const float4*)src)[0];
            float4 f1 = ((const float4*)src)[1];
            float4 f2 = ((const float4*)src)[2];
            float4 f3 = ((const float4*)src)[3];
            uint4 w0, w1;
            w0.x = pk2(f0.x, f0.y); w0.y = pk2(f0.z, f0.w);
            w0.z = pk2(f1.x, f1.y); w0.w = pk2(f1.z, f1.w);
            w1.x = pk2(f2.x, f2.y); w1.y = pk2(f2.z, f2.w);
            w1.z = pk2(f3.x, f3.y); w1.w = pk2(f3.z, f3.w);
            *(uint4*)(sK + srow * 128 + (((c4 * 2)     ^ (srow & 7)) * 16)) = w0;
            *(uint4*)(sK + srow * 128 + (((c4 * 2 + 1) ^ (srow & 7)) * 16)) = w1;
        }
        // ---- stage V^T tile (scattered u16 writes) ----
        {
            const float* src = vbase + (size_t)(k0 + srow) * kD + c4 * 16;
            int kg = srow >> 3;
            int kb2 = (srow & 7) * 2;
            #pragma unroll
            for (int j = 0; j < 4; ++j) {
                float4 f = ((const float4*)src)[j];
                int dbase = c4 * 16 + j * 4;
                *(unsigned short*)(sVT + (dbase + 0) * 128 + ((kg ^ ((dbase + 0) & 7)) * 16) + kb2) = bf1(f.x);
                *(unsigned short*)(sVT + (dbase + 1) * 128 + ((kg ^ ((dbase + 1) & 7)) * 16) + kb2) = bf1(f.y);
                *(unsigned short*)(sVT + (dbase + 2) * 128 + ((kg ^ ((dbase + 2) & 7)) * 16) + kb2) = bf1(f.z);
                *(unsigned short*)(sVT + (dbase + 3) * 128 + ((kg ^ ((dbase + 3) & 7)) * 16) + kb2) = bf1(f.w);
            }
        }
        __syncthreads();

        // ---- S = (Q/8) K^T : 4 fragments over k-cols ----
        f32x4 s[4];
        #pragma unroll
        for (int nj = 0; nj < 4; ++nj) { s[nj][0] = 0; s[nj][1] = 0; s[nj][2] = 0; s[nj][3] = 0; }
        #pragma unroll
        for (int nj = 0; nj < 4; ++nj) {
            int krow = nj * 16 + fr;
            short8v bk0 = *(const short8v*)(sK + krow * 128 + (((g4)     ^ (fr & 7)) * 16));
            short8v bk1 = *(const short8v*)(sK + krow * 128 + (((4 + g4) ^ (fr & 7)) * 16));
            s[nj] = __builtin_amdgcn_mfma_f32_16x16x32_bf16(aq[0], bk0, s[nj], 0, 0, 0);
            s[nj] = __builtin_amdgcn_mfma_f32_16x16x32_bf16(aq[1], bk1, s[nj], 0, 0, 0);
        }

        // ---- causal mask on the diagonal tile ----
        if (t == qt) {
            #pragma unroll
            for (int nj = 0; nj < 4; ++nj)
                #pragma unroll
                for (int r = 0; r < 4; ++r) {
                    int qq = w * 16 + g4 * 4 + r;
                    int kk = nj * 16 + fr;
                    if (kk > qq) s[nj][r] = -1e30f;
                }
        }

        // ---- online softmax (per q-row; rows live in (g4,r), k in (nj,fr)) ----
        float tm[4];
        #pragma unroll
        for (int r = 0; r < 4; ++r)
            tm[r] = fmaxf(fmaxf(s[0][r], s[1][r]), fmaxf(s[2][r], s[3][r]));
        #pragma unroll
        for (int mk = 1; mk <= 8; mk <<= 1)
            #pragma unroll
            for (int r = 0; r < 4; ++r)
                tm[r] = fmaxf(tm[r], __shfl_xor(tm[r], mk));

        float scl[4];
        #pragma unroll
        for (int r = 0; r < 4; ++r) {
            float mnew = fmaxf(mrow[r], tm[r]);
            scl[r] = __expf(mrow[r] - mnew);
            mrow[r] = mnew;
        }
        float ps[4][4];
        float psum[4];
        #pragma unroll
        for (int r = 0; r < 4; ++r) {
            ps[0][r] = __expf(s[0][r] - mrow[r]);
            ps[1][r] = __expf(s[1][r] - mrow[r]);
            ps[2][r] = __expf(s[2][r] - mrow[r]);
            ps[3][r] = __expf(s[3][r] - mrow[r]);
            psum[r] = ps[0][r] + ps[1][r] + ps[2][r] + ps[3][r];
        }
        #pragma unroll
        for (int mk = 1; mk <= 8; mk <<= 1)
            #pragma unroll
            for (int r = 0; r < 4; ++r)
                psum[r] += __shfl_xor(psum[r], mk);
        #pragma unroll
        for (int r = 0; r < 4; ++r)
            lrow[r] = lrow[r] * scl[r] + psum[r];
        #pragma unroll
        for (int nj = 0; nj < 4; ++nj)
            #pragma unroll
            for (int r = 0; r < 4; ++r)
                accO[nj][r] *= scl[r];

        // ---- P -> per-wave LDS (bf16), then PV via MFMA ----
        #pragma unroll
        for (int nj = 0; nj < 4; ++nj) {
            int kk = nj * 16 + fr;
            int kg = nj * 2 + (fr >> 3);
            #pragma unroll
            for (int r = 0; r < 4; ++r) {
                int qq = g4 * 4 + r;
                *(unsigned short*)(sP[w] + qq * 128 + ((kg ^ (qq & 7)) * 16) + (fr & 7) * 2) = bf1(ps[nj][r]);
            }
        }
        #pragma unroll
        for (int ks = 0; ks < 2; ++ks) {
            short8v ap = *(const short8v*)(sP[w] + fr * 128 + (((ks * 4 + g4) ^ (fr & 7)) * 16));
            #pragma unroll
            for (int nj = 0; nj < 4; ++nj) {
                int drow = nj * 16 + fr;
                short8v bv_ = *(const short8v*)(sVT + drow * 128 + (((ks * 4 + g4) ^ (fr & 7)) * 16));
                accO[nj] = __builtin_amdgcn_mfma_f32_16x16x32_bf16(ap, bv_, accO[nj], 0, 0, 0);
            }
        }
    }

    // ---- epilogue: O / l ----
    float invl[4];
    #pragma unroll
    for (int r = 0; r < 4; ++r) invl[r] = 1.0f / lrow[r];
    #pragma unroll
    for (int nj = 0; nj < 4; ++nj) {
        #pragma unroll
        for (int r = 0; r < 4; ++r) {
            int qg = q0 + w * 16 + g4 * 4 + r;
            int d = nj * 16 + fr;
            y[(size_t)(b * kT + qg) * kD + h * kDH + d] = accO[nj][r] * invl[r];
        }
    }
}

// ---------------------------------------------------------------------------
// Host-side launch
// ---------------------------------------------------------------------------
extern "C" void kernel_launch(void* const* d_in, const int* in_sizes, int n_in,
                              void* d_out, int out_size, void* d_ws, size_t ws_size,
                              hipStream_t stream)
{
    const int*   tokens = (const int*)  d_in[0];
    const float* emb    = (const float*)d_in[1];
    const float* pos    = (const float*)d_in[2];
    const float* ln1_s  = (const float*)d_in[3];
    const float* ln1_b  = (const float*)d_in[4];
    const float* Wq     = (const float*)d_in[5];
    const float* bq     = (const float*)d_in[6];
    const float* Wk     = (const float*)d_in[7];
    const float* bk     = (const float*)d_in[8];
    const float* Wv     = (const float*)d_in[9];
    const float* bv     = (const float*)d_in[10];
    const float* Wo     = (const float*)d_in[11];
    const float* bo     = (const float*)d_in[12];
    const float* ln2_s  = (const float*)d_in[13];
    const float* ln2_b  = (const float*)d_in[14];
    const float* W1     = (const float*)d_in[15];
    const float* b1     = (const float*)d_in[16];
    const float* W2     = (const float*)d_in[17];
    const float* b2     = (const float*)d_in[18];
    const float* lnf_s  = (const float*)d_in[19];
    const float* lnf_b  = (const float*)d_in[20];
    const float* Wl     = (const float*)d_in[21];
    const float* bl     = (const float*)d_in[22];
    float* out = (float*)d_out;

    size_t BTD = (size_t)kRows * kD;    // 2,097,152 floats
    float* ws  = (float*)d_ws;
    float* x   = ws;                    // residual stream
    float* h   = x + BTD;               // LN output / attn out (reused)
    float* qb  = h + BTD;
    float* kb  = qb + BTD;
    float* vb  = kb + BTD;
    float* mid = qb;                    // FFN mid (4*BTD) aliases qb..vb
    // total ws: 6*BTD*4B = 50.3 MB

    embed_kernel<<<kRows, 256, 0, stream>>>(tokens, emb, pos, x);

    dim3 gQkv(kD / 64, kRows / 128, 3);       // 16 x 16 x 3 (128x64 tiles)
    dim3 gProj(kD / 64, kRows / 128);         // 16 x 16    (128x64 tiles)
    dim3 gFfn1(4 * kD / 128, kRows / 128);    // 32 x 16    (128x128 tiles)
    dim3 gLogit(kV / 128, kRows / 128);       // 250 x 16   (128x128 tiles)
    dim3 gAttn(kT / 64, kH, kB);              // 16 x 16 x 2

    for (int i = 0; i < kL; ++i) {
        size_t oD  = (size_t)i * kD;
        size_t oDD = (size_t)i * kD * kD;
        size_t oD4 = (size_t)i * 4 * kD;
        size_t oDD4 = (size_t)i * kD * 4 * kD;

        ln_kernel<<<kRows, 256, 0, stream>>>(x, ln1_s + oD, ln1_b + oD, h);

        mgemm_qkv_kernel<<<gQkv, 256, 0, stream>>>(h,
            Wq + oDD, bq + oD, qb,
            Wk + oDD, bk + oD, kb,
            Wv + oDD, bv + oD, vb);

        fattn_kernel<<<gAttn, 256, 0, stream>>>(qb, kb, vb, h);

        mgemm_kernel<128, 64, 1><<<gProj, 256, 0, stream>>>(h, Wo + oDD, bo + oD, x, x, kD, kD);

        ln_kernel<<<kRows, 256, 0, stream>>>(x, ln2_s + oD, ln2_b + oD, h);

        mgemm_kernel<128, 128, 2><<<gFfn1, 256, 0, stream>>>(h, W1 + oDD4, b1 + oD4, nullptr, mid, 4 * kD, kD);
        mgemm_kernel<128, 64, 1><<<gProj, 256, 0, stream>>>(mid, W2 + oDD4, b2 + oD, x, x, kD, 4 * kD);
    }

    ln_kernel<<<kRows, 256, 0, stream>>>(x, lnf_s, lnf_b, h);
    mgemm_kernel<128, 128, 0><<<gLogit, 256, 0, stream>>>(h, Wl, bl, nullptr, out, kV, kD);
}